// Round 3
// baseline (36.767 us; speedup 1.0000x reference)
//
#include <hip/hip_runtime.h>
#include <math.h>

constexpr int CIN = 32;   // input channels (K)
constexpr int NS  = 32;   // sums (output channels)
constexpr int TPW = 4;    // tiles (of 32 pixels) per wave

typedef __attribute__((ext_vector_type(8)))  short  short8;
typedef __attribute__((ext_vector_type(16))) float  f32x16;

__device__ __forceinline__ short f2bf(float f) {
    union { float f; unsigned u; } v; v.f = f;
    unsigned r = (v.u + 0x7FFFu + ((v.u >> 16) & 1u)) >> 16;   // RNE
    return (short)r;
}

// Fused: per-wave w-fragment softmax (from acc directly) + pipelined
// 4-tile main loop. One wave = 4x 32 pixels via mfma_f32_32x32x16_bf16.
// A frag (w):  lane holds row s=lane&31, k=8*(lane>>5)+j
// B frag (p):  lane holds col pix=lane&31, k=8*(lane>>5)+j
// D:           lane holds col pix, rows s=(reg&3)+8*(reg>>2)+4*(lane>>5)
__global__ __launch_bounds__(256)
void logconv_fused(const float* __restrict__ x,
                   const float* __restrict__ acc,
                   float* __restrict__ out) {
    const int lane = threadIdx.x & 63;
    const int wid  = threadIdx.x >> 6;
    const int r    = lane & 31;          // pixel-in-tile / s-row for A
    const int h    = lane >> 5;          // K-half

    // ---- per-lane A fragment: column s=r of softmax_c(acc[c][s]) ----
    float a[CIN];
#pragma unroll
    for (int c = 0; c < CIN; ++c) a[c] = acc[c * NS + r];   // broadcast-coalesced
    float wm = a[0];
#pragma unroll
    for (int c = 1; c < CIN; ++c) wm = fmaxf(wm, a[c]);
    float wsum = 0.f;
#pragma unroll
    for (int c = 0; c < CIN; ++c) { a[c] = __expf(a[c] - wm); wsum += a[c]; }
    float winv = 1.f / wsum;
    short8 w0, w1;
#pragma unroll
    for (int j = 0; j < 8; ++j) {        // static indices only (rule #20)
        w0[j] = f2bf((h ? a[8 + j]  : a[j])      * winv);
        w1[j] = f2bf((h ? a[24 + j] : a[16 + j]) * winv);
    }

    const long gw   = (long)blockIdx.x * 4 + wid;   // global wave id
    const long pix0 = gw * (32 * TPW) + r;

#define LOADT(T, R0, R1, R2, R3) do {                                   \
        const float* xp_ = x + (pix0 + (T) * 32) * CIN + 8 * h;         \
        R0 = *(const float4*)(xp_);                                     \
        R1 = *(const float4*)(xp_ + 4);                                 \
        R2 = *(const float4*)(xp_ + 16);                                \
        R3 = *(const float4*)(xp_ + 20);                                \
    } while (0)

#define COMPUTE(T, R0, R1, R2, R3) do {                                 \
        float xv[16] = {R0.x,R0.y,R0.z,R0.w, R1.x,R1.y,R1.z,R1.w,       \
                        R2.x,R2.y,R2.z,R2.w, R3.x,R3.y,R3.z,R3.w};      \
        float pm = xv[0];                                               \
        _Pragma("unroll")                                               \
        for (int j = 1; j < 16; ++j) pm = fmaxf(pm, xv[j]);             \
        pm = fmaxf(pm, __shfl_xor(pm, 32));                             \
        short8 p0, p1;                                                  \
        _Pragma("unroll")                                               \
        for (int j = 0; j < 8; ++j) p0[j] = f2bf(__expf(xv[j]     - pm)); \
        _Pragma("unroll")                                               \
        for (int j = 0; j < 8; ++j) p1[j] = f2bf(__expf(xv[8 + j] - pm)); \
        f32x16 accv;                                                    \
        _Pragma("unroll")                                               \
        for (int i = 0; i < 16; ++i) accv[i] = 0.f;                     \
        accv = __builtin_amdgcn_mfma_f32_32x32x16_bf16(w0, p0, accv, 0, 0, 0); \
        accv = __builtin_amdgcn_mfma_f32_32x32x16_bf16(w1, p1, accv, 0, 0, 0); \
        float* op_ = out + (pix0 + (T) * 32) * NS;                      \
        _Pragma("unroll")                                               \
        for (int g = 0; g < 4; ++g) {                                   \
            float4 v;                                                   \
            v.x = pm + __logf(accv[4 * g + 0]);                         \
            v.y = pm + __logf(accv[4 * g + 1]);                         \
            v.z = pm + __logf(accv[4 * g + 2]);                         \
            v.w = pm + __logf(accv[4 * g + 3]);                         \
            *(float4*)(op_ + 8 * g + 4 * h) = v;                        \
        }                                                               \
    } while (0)

    // 2-deep software pipeline over 4 tiles (named regs, fully static)
    float4 c0, c1, c2, c3, n0, n1, n2, n3;
    LOADT(0, c0, c1, c2, c3);
    LOADT(1, n0, n1, n2, n3);
    COMPUTE(0, c0, c1, c2, c3);
    c0 = n0; c1 = n1; c2 = n2; c3 = n3;
    LOADT(2, n0, n1, n2, n3);
    COMPUTE(1, c0, c1, c2, c3);
    c0 = n0; c1 = n1; c2 = n2; c3 = n3;
    LOADT(3, n0, n1, n2, n3);
    COMPUTE(2, c0, c1, c2, c3);
    COMPUTE(3, n0, n1, n2, n3);
#undef LOADT
#undef COMPUTE
}

extern "C" void kernel_launch(void* const* d_in, const int* in_sizes, int n_in,
                              void* d_out, int out_size, void* d_ws, size_t ws_size,
                              hipStream_t stream) {
    const float* x   = (const float*)d_in[0];   // [32,128,128,32] f32
    const float* acc = (const float*)d_in[1];   // [1,1,32,32] f32
    float* out = (float*)d_out;

    int npix = in_sizes[0] / CIN;               // 524288
    int pixels_per_block = 4 /*waves*/ * TPW * 32;   // 512
    int grid = npix / pixels_per_block;         // 1024
    logconv_fused<<<grid, 256, 0, stream>>>(x, acc, out);
}